// Round 1
// baseline (1222.156 us; speedup 1.0000x reference)
//
#include <hip/hip_runtime.h>
#include <math.h>

#define NT 2048
#define HID 768
#define NC 40960
#define NFEAT 20
#define UN 1024
#define SDIM 2324
#define NTOP 512
#define WMAX 20

// d_out element offsets (all f32)
#define OFF_IDX   95191040
#define OFF_S     95191552
#define OFF_E     95192064
#define OFF_PEMB  95192576
#define OFF_SC    96382464
#define OFF_SP    96382976

// ---------------- tok_att: one wave per token ----------------
__global__ __launch_bounds__(256) void k_tok_att(const float* __restrict__ hidden,
                                                 const float* __restrict__ w_attn,
                                                 const float* __restrict__ b_attn,
                                                 float* __restrict__ tok_att) {
  int wave = (blockIdx.x * blockDim.x + threadIdx.x) >> 6;
  int lane = threadIdx.x & 63;
  if (wave >= NT) return;
  const float* row = hidden + (size_t)wave * HID;
  float s = 0.f;
  for (int c = lane; c < HID; c += 64) s += row[c] * w_attn[c];
  #pragma unroll
  for (int off = 32; off; off >>= 1) s += __shfl_down(s, off);
  if (lane == 0) tok_att[wave] = s + b_attn[0];
}

// ---------------- Pc[w][j] = emb_width[w] @ W1 rows [1536,1556) ----------------
__global__ __launch_bounds__(256) void k_pc(const float* __restrict__ emb_width,
                                            const float* __restrict__ W1,
                                            float* __restrict__ Pc) {
  int idx = blockIdx.x * 256 + threadIdx.x;   // w*1024 + j
  int w = idx >> 10, j = idx & 1023;
  float s = 0.f;
  #pragma unroll
  for (int k = 0; k < NFEAT; ++k) s += emb_width[w * NFEAT + k] * W1[(size_t)(2 * HID + k) * UN + j];
  Pc[idx] = s;
}

// ---------------- prior[w] = relu(ewp[w]@Wp1+bp1)@Wp2 + bp2 ----------------
__global__ __launch_bounds__(256) void k_prior(const float* __restrict__ ewp,
                                               const float* __restrict__ Wp1,
                                               const float* __restrict__ bp1,
                                               const float* __restrict__ Wp2,
                                               const float* __restrict__ bp2,
                                               float* __restrict__ prior) {
  int w = blockIdx.x;
  int tid = threadIdx.x;
  __shared__ float red[256];
  float local = 0.f;
  for (int j = tid; j < UN; j += 256) {
    float hp = bp1[j];
    #pragma unroll
    for (int k = 0; k < NFEAT; ++k) hp += ewp[w * NFEAT + k] * Wp1[k * UN + j];
    local += fmaxf(hp, 0.f) * Wp2[j];
  }
  red[tid] = local;
  __syncthreads();
  for (int st = 128; st > 0; st >>= 1) { if (tid < st) red[tid] += red[tid + st]; __syncthreads(); }
  if (tid == 0) prior[w] = red[0] + bp2[0];
}

// ---------------- P = hidden @ [W1a | W1b | W1d]  (2048 x 3072, K=768) ----------------
__global__ __launch_bounds__(256) void k_matmul_P(const float* __restrict__ hidden,
                                                  const float* __restrict__ W1,
                                                  float* __restrict__ P) {
  __shared__ float As[16][64];  // [k][m]
  __shared__ float Bs[16][64];  // [k][n]
  int bn = blockIdx.x, bm = blockIdx.y;
  int n0 = bn * 64;
  int seg = n0 >> 10;
  int rowbase = (seg == 0) ? 0 : (seg == 1 ? HID : (2 * HID + NFEAT));
  int j0 = n0 & 1023;
  int tid = threadIdx.x;
  int tx = tid & 15, ty = tid >> 4;
  int lr = tid >> 2;           // A load row 0..63
  int lk = (tid & 3) * 4;      // A load k offset
  int bk = tid >> 4;           // B load k 0..15
  int bc = (tid & 15) * 4;     // B load col
  float acc[4][4] = {};
  for (int k0 = 0; k0 < HID; k0 += 16) {
    float4 a = *(const float4*)&hidden[(size_t)(bm * 64 + lr) * HID + k0 + lk];
    As[lk + 0][lr] = a.x; As[lk + 1][lr] = a.y; As[lk + 2][lr] = a.z; As[lk + 3][lr] = a.w;
    float4 b = *(const float4*)&W1[(size_t)(rowbase + k0 + bk) * UN + j0 + bc];
    *(float4*)&Bs[bk][bc] = b;
    __syncthreads();
    #pragma unroll
    for (int k = 0; k < 16; ++k) {
      float4 a4 = *(const float4*)&As[k][ty * 4];
      float4 b4 = *(const float4*)&Bs[k][tx * 4];
      float av[4] = {a4.x, a4.y, a4.z, a4.w};
      float bv[4] = {b4.x, b4.y, b4.z, b4.w};
      #pragma unroll
      for (int i = 0; i < 4; ++i)
        #pragma unroll
        for (int jj = 0; jj < 4; ++jj) acc[i][jj] += av[i] * bv[jj];
    }
    __syncthreads();
  }
  #pragma unroll
  for (int i = 0; i < 4; ++i) {
    float4 o = make_float4(acc[i][0], acc[i][1], acc[i][2], acc[i][3]);
    *(float4*)&P[(size_t)(bm * 64 + ty * 4 + i) * 3072 + n0 + tx * 4] = o;
  }
}

// ---------------- fused span_emb write + score + sort key ----------------
__global__ __launch_bounds__(256) void k_span(
    const float* __restrict__ hidden, const int* __restrict__ starts, const int* __restrict__ ends,
    const float* __restrict__ tok_att, const float* __restrict__ emb_width,
    const float* __restrict__ P, const float* __restrict__ Pc,
    const float* __restrict__ b1, const float* __restrict__ W2,
    const float* __restrict__ b2ptr, const float* __restrict__ prior,
    float* __restrict__ out, float* __restrict__ scores, unsigned long long* __restrict__ keys) {
  int i = blockIdx.x;
  int s = starts[i], e = ends[i];
  int w = e - s;
  int L = w + 1;
  int tid = threadIdx.x;
  __shared__ float alpha[WMAX];
  __shared__ float red[256];
  if (tid < 64) {
    float v = (tid < L) ? tok_att[s + tid] : -3.0e38f;
    float m = v;
    #pragma unroll
    for (int off = 32; off; off >>= 1) m = fmaxf(m, __shfl_xor(m, off));
    float ex = (tid < L) ? expf(v - m) : 0.0f;
    float sum = ex;
    #pragma unroll
    for (int off = 32; off; off >>= 1) sum += __shfl_xor(sum, off);
    if (tid < L) alpha[tid] = ex / sum;
  }
  __syncthreads();
  // span_emb row (2324 = 581 float4s; all segment boundaries are multiples of 4)
  const float* hs = hidden + (size_t)s * HID;
  const float* he = hidden + (size_t)e * HID;
  float* orow = out + (size_t)i * SDIM;
  for (int q = tid; q < SDIM / 4; q += 256) {
    int c = q * 4;
    float4 v;
    if (c < HID) v = *(const float4*)(hs + c);
    else if (c < 2 * HID) v = *(const float4*)(he + (c - HID));
    else if (c < 2 * HID + NFEAT) v = *(const float4*)(emb_width + w * NFEAT + (c - 2 * HID));
    else {
      int cc = c - (2 * HID + NFEAT);
      float ax = 0, ay = 0, az = 0, aw = 0;
      for (int t = 0; t < L; ++t) {
        float a = alpha[t];
        float4 hv = *(const float4*)(hidden + (size_t)(s + t) * HID + cc);
        ax += a * hv.x; ay += a * hv.y; az += a * hv.z; aw += a * hv.w;
      }
      v = make_float4(ax, ay, az, aw);
    }
    *(float4*)(orow + c) = v;
  }
  // score: pre_h = b1 + Pa[s] + Pb[e] + Pc[w] + sum_t alpha_t * Pd[s+t]
  int j = tid * 4;
  float4 pre = *(const float4*)(b1 + j);
  float4 pa = *(const float4*)(P + (size_t)s * 3072 + j);
  float4 pb = *(const float4*)(P + (size_t)e * 3072 + 1024 + j);
  float4 pc = *(const float4*)(Pc + w * UN + j);
  pre.x += pa.x + pb.x + pc.x;
  pre.y += pa.y + pb.y + pc.y;
  pre.z += pa.z + pb.z + pc.z;
  pre.w += pa.w + pb.w + pc.w;
  for (int t = 0; t < L; ++t) {
    float a = alpha[t];
    float4 pd = *(const float4*)(P + (size_t)(s + t) * 3072 + 2048 + j);
    pre.x += a * pd.x; pre.y += a * pd.y; pre.z += a * pd.z; pre.w += a * pd.w;
  }
  float4 w2 = *(const float4*)(W2 + j);
  float local = fmaxf(pre.x, 0.f) * w2.x + fmaxf(pre.y, 0.f) * w2.y +
                fmaxf(pre.z, 0.f) * w2.z + fmaxf(pre.w, 0.f) * w2.w;
  red[tid] = local;
  __syncthreads();
  for (int st = 128; st > 0; st >>= 1) { if (tid < st) red[tid] += red[tid + st]; __syncthreads(); }
  if (tid == 0) {
    float sc = red[0] + b2ptr[0] + prior[w];
    scores[i] = sc;
    unsigned u = __float_as_uint(sc);
    u = (u >> 31) ? ~u : (u | 0x80000000u);        // ascending-order map
    unsigned inv = ~u;                             // descending score
    keys[i] = (((unsigned long long)inv) << 32) | (unsigned)i;  // tie: smaller idx first
  }
}

// ---------------- exact argsort via O(n^2) ranking on u64 keys ----------------
__global__ void k_zero(int* __restrict__ rank) { rank[blockIdx.x * 256 + threadIdx.x] = 0; }

__global__ __launch_bounds__(256) void k_rank(const unsigned long long* __restrict__ keys,
                                              int* __restrict__ rank) {
  int ic = blockIdx.x >> 5;     // 20 i-chunks of 2048
  int jc = blockIdx.x & 31;     // 32 j-chunks of 1280
  int tid = threadIdx.x;
  int ibase = ic * 2048 + tid;
  unsigned long long mk[8];
  int cnt[8];
  #pragma unroll
  for (int k = 0; k < 8; ++k) { mk[k] = keys[ibase + k * 256]; cnt[k] = 0; }
  int j0 = jc * 1280;
  #pragma unroll 4
  for (int j = j0; j < j0 + 1280; ++j) {
    unsigned long long kj = keys[j];   // wave-uniform -> scalar load
    #pragma unroll
    for (int k = 0; k < 8; ++k) cnt[k] += (kj < mk[k]) ? 1 : 0;
  }
  #pragma unroll
  for (int k = 0; k < 8; ++k) if (cnt[k]) atomicAdd(&rank[ibase + k * 256], cnt[k]);
}

__global__ void k_scatter(const int* __restrict__ rank, int* __restrict__ order) {
  int i = blockIdx.x * 256 + threadIdx.x;
  order[rank[i]] = i;
}

// ---------------- sequential greedy NMS scan: single wave, state in LDS ----------------
__global__ void k_scan(const int* __restrict__ order,
                       const int* __restrict__ starts,
                       const int* __restrict__ ends,
                       int* __restrict__ acc_idx, int* __restrict__ acc_s,
                       int* __restrict__ acc_e, int* __restrict__ acc_count) {
  __shared__ int LE[NT];
  __shared__ int ES[NT];
  int lane = threadIdx.x;
  for (int t = lane; t < NT; t += 64) { LE[t] = -1; ES[t] = NT; }
  __syncthreads();
  int count = 0;
  for (int base = 0; base < NC && count < NTOP; base += 64) {
    int ci = order[base + lane];
    int sv = starts[ci];
    int ev = ends[ci];
    for (int t = 0; t < 64; ++t) {
      int s = __shfl(sv, t);
      int e = __shfl(ev, t);
      int tok = s + lane;
      int tokc = (tok <= e) ? tok : e;   // clamped, always in-bounds
      int le = LE[tokc];
      int es = ES[tokc];
      bool c1 = (lane >= 1) && (tok <= e) && (le > e);   // tok in (s,e], latest_end[tok] > e
      bool c2 = (tok < e) && (es < s);                   // tok in [s,e), earliest_start[tok] < s
      bool cross = __any(c1 || c2);
      if (!cross) {
        int cid = __shfl(ci, t);    // uniform path: all lanes execute
        if (lane == 0) {
          acc_idx[count] = cid;
          acc_s[count] = s;
          acc_e[count] = e;
          LE[s] = (LE[s] > e) ? LE[s] : e;
          ES[e] = (ES[e] < s) ? ES[e] : s;
        }
        count++;
        if (count >= NTOP) break;
      }
      __syncthreads();   // single-wave barrier: orders LDS writes vs next iter reads
    }
  }
  if (lane == 0) acc_count[0] = count;
}

// ---------------- sort accepted by (start,end), write scalar outputs ----------------
__global__ __launch_bounds__(512) void k_outputs(const int* __restrict__ acc_idx,
                                                 const int* __restrict__ acc_s,
                                                 const int* __restrict__ acc_e,
                                                 const int* __restrict__ acc_count,
                                                 const float* __restrict__ scores,
                                                 const int* __restrict__ speaker,
                                                 float* __restrict__ out,
                                                 int* __restrict__ sortedIdx) {
  __shared__ int ks[NTOP];
  int tid = threadIdx.x;
  int count = acc_count[0];
  int key = 0x7FFFFFFF;
  if (tid < count) key = acc_s[tid] * (NT + 1) + acc_e[tid];
  ks[tid] = key;
  __syncthreads();
  if (tid < count) {
    int r = 0;
    for (int b = 0; b < count; ++b) {
      int kb = ks[b];
      r += ((kb < key) || (kb == key && b < tid)) ? 1 : 0;
    }
    int ci = acc_idx[tid];
    out[OFF_IDX + r] = (float)ci;
    out[OFF_S + r]   = (float)acc_s[tid];
    out[OFF_E + r]   = (float)acc_e[tid];
    out[OFF_SC + r]  = scores[ci];
    out[OFF_SP + r]  = (float)speaker[acc_s[tid]];
    sortedIdx[r] = ci;
  }
  __syncthreads();
  if (tid >= count) {   // ref: where(valid, picked, picked[0])
    out[OFF_IDX + tid] = out[OFF_IDX];
    out[OFF_S + tid]   = out[OFF_S];
    out[OFF_E + tid]   = out[OFF_E];
    out[OFF_SC + tid]  = out[OFF_SC];
    out[OFF_SP + tid]  = out[OFF_SP];
    sortedIdx[tid] = sortedIdx[0];
  }
}

// ---------------- gather pruned_emb rows from span_emb region of d_out ----------------
__global__ __launch_bounds__(256) void k_copy_emb(const int* __restrict__ sortedIdx,
                                                  float* __restrict__ out) {
  int r = blockIdx.x;
  int ci = sortedIdx[r];
  const float* src = out + (size_t)ci * SDIM;
  float* dst = out + OFF_PEMB + (size_t)r * SDIM;
  for (int q = threadIdx.x; q < SDIM / 4; q += 256) {
    ((float4*)dst)[q] = ((const float4*)src)[q];
  }
}

extern "C" void kernel_launch(void* const* d_in, const int* in_sizes, int n_in,
                              void* d_out, int out_size, void* d_ws, size_t ws_size,
                              hipStream_t stream) {
  const float* hidden   = (const float*)d_in[0];
  const int*   starts   = (const int*)d_in[1];
  const int*   ends     = (const int*)d_in[2];
  const int*   speaker  = (const int*)d_in[3];
  const float* w_attn   = (const float*)d_in[4];
  const float* b_attn   = (const float*)d_in[5];
  const float* W1       = (const float*)d_in[6];
  const float* b1       = (const float*)d_in[7];
  const float* W2       = (const float*)d_in[8];
  const float* b2       = (const float*)d_in[9];
  const float* embw     = (const float*)d_in[10];
  const float* ewp      = (const float*)d_in[11];
  const float* Wp1      = (const float*)d_in[12];
  const float* bp1      = (const float*)d_in[13];
  const float* Wp2      = (const float*)d_in[14];
  const float* bp2      = (const float*)d_in[15];
  float* out = (float*)d_out;

  float* f = (float*)d_ws;
  float* P       = f;                    // 2048*3072
  float* tok_att = P + 6291456;          // 2048
  float* Pc      = tok_att + 2048;       // 20*1024
  float* prior   = Pc + 20480;           // 20 (pad 32)
  float* scores  = prior + 32;           // 40960
  unsigned long long* keys = (unsigned long long*)(scores + 40960);  // 40960 (8B-aligned)
  int* rank      = (int*)(keys + 40960);
  int* order     = rank + 40960;
  int* acc_idx   = order + 40960;
  int* acc_s     = acc_idx + NTOP;
  int* acc_e     = acc_s + NTOP;
  int* acc_count = acc_e + NTOP;
  int* sortedIdx = acc_count + 4;

  k_tok_att<<<dim3(512), dim3(256), 0, stream>>>(hidden, w_attn, b_attn, tok_att);
  k_pc<<<dim3(80), dim3(256), 0, stream>>>(embw, W1, Pc);
  k_prior<<<dim3(20), dim3(256), 0, stream>>>(ewp, Wp1, bp1, Wp2, bp2, prior);
  k_zero<<<dim3(160), dim3(256), 0, stream>>>(rank);
  k_matmul_P<<<dim3(48, 32), dim3(256), 0, stream>>>(hidden, W1, P);
  k_span<<<dim3(NC), dim3(256), 0, stream>>>(hidden, starts, ends, tok_att, embw, P, Pc,
                                             b1, W2, b2, prior, out, scores, keys);
  k_rank<<<dim3(640), dim3(256), 0, stream>>>(keys, rank);
  k_scatter<<<dim3(160), dim3(256), 0, stream>>>(rank, order);
  k_scan<<<dim3(1), dim3(64), 0, stream>>>(order, starts, ends, acc_idx, acc_s, acc_e, acc_count);
  k_outputs<<<dim3(1), dim3(512), 0, stream>>>(acc_idx, acc_s, acc_e, acc_count, scores,
                                               speaker, out, sortedIdx);
  k_copy_emb<<<dim3(NTOP), dim3(256), 0, stream>>>(sortedIdx, out);
}

// Round 2
// 1031.042 us; speedup vs baseline: 1.1854x; 1.1854x over previous
//
#include <hip/hip_runtime.h>
#include <math.h>

#define NT 2048
#define HID 768
#define NC 40960
#define NFEAT 20
#define UN 1024
#define SDIM 2324
#define NTOP 512
#define WMAX 20

// d_out element offsets (all f32)
#define OFF_IDX   95191040
#define OFF_S     95191552
#define OFF_E     95192064
#define OFF_PEMB  95192576
#define OFF_SC    96382464
#define OFF_SP    96382976

// ---------------- generic zero ----------------
__global__ void k_zero(int* __restrict__ p, int n) {
  int i = blockIdx.x * 256 + threadIdx.x;
  if (i < n) p[i] = 0;
}

// ---------------- counting sort of candidates by start token ----------------
__global__ void k_hist(const int* __restrict__ starts, int* __restrict__ hist) {
  int i = blockIdx.x * 256 + threadIdx.x;
  atomicAdd(&hist[starts[i]], 1);
}

__global__ __launch_bounds__(256) void k_prefix(const int* __restrict__ hist,
                                                int* __restrict__ cursor) {
  __shared__ int tsum[256];
  int tid = threadIdx.x;
  int v[8], pre[8];
  int s = 0;
  #pragma unroll
  for (int j = 0; j < 8; ++j) { v[j] = hist[tid * 8 + j]; pre[j] = s; s += v[j]; }
  tsum[tid] = s;
  __syncthreads();
  for (int off = 1; off < 256; off <<= 1) {
    int t = (tid >= off) ? tsum[tid - off] : 0;
    __syncthreads();
    tsum[tid] += t;
    __syncthreads();
  }
  int base = (tid > 0) ? tsum[tid - 1] : 0;
  #pragma unroll
  for (int j = 0; j < 8; ++j) cursor[tid * 8 + j] = base + pre[j];
}

__global__ void k_place(const int* __restrict__ starts, int* __restrict__ cursor,
                        int* __restrict__ ord) {
  int i = blockIdx.x * 256 + threadIdx.x;
  int pos = atomicAdd(&cursor[starts[i]], 1);
  ord[pos] = i;
}

// ---------------- tok_att: one wave per token ----------------
__global__ __launch_bounds__(256) void k_tok_att(const float* __restrict__ hidden,
                                                 const float* __restrict__ w_attn,
                                                 const float* __restrict__ b_attn,
                                                 float* __restrict__ tok_att) {
  int wave = (blockIdx.x * blockDim.x + threadIdx.x) >> 6;
  int lane = threadIdx.x & 63;
  if (wave >= NT) return;
  const float* row = hidden + (size_t)wave * HID;
  float s = 0.f;
  for (int c = lane; c < HID; c += 64) s += row[c] * w_attn[c];
  #pragma unroll
  for (int off = 32; off; off >>= 1) s += __shfl_down(s, off);
  if (lane == 0) tok_att[wave] = s + b_attn[0];
}

// ---------------- Pc[w][j] = emb_width[w] @ W1 rows [1536,1556) ----------------
__global__ __launch_bounds__(256) void k_pc(const float* __restrict__ emb_width,
                                            const float* __restrict__ W1,
                                            float* __restrict__ Pc) {
  int idx = blockIdx.x * 256 + threadIdx.x;   // w*1024 + j
  int w = idx >> 10, j = idx & 1023;
  float s = 0.f;
  #pragma unroll
  for (int k = 0; k < NFEAT; ++k) s += emb_width[w * NFEAT + k] * W1[(size_t)(2 * HID + k) * UN + j];
  Pc[idx] = s;
}

// ---------------- prior[w] = relu(ewp[w]@Wp1+bp1)@Wp2 + bp2 ----------------
__global__ __launch_bounds__(256) void k_prior(const float* __restrict__ ewp,
                                               const float* __restrict__ Wp1,
                                               const float* __restrict__ bp1,
                                               const float* __restrict__ Wp2,
                                               const float* __restrict__ bp2,
                                               float* __restrict__ prior) {
  int w = blockIdx.x;
  int tid = threadIdx.x;
  __shared__ float red[256];
  float local = 0.f;
  for (int j = tid; j < UN; j += 256) {
    float hp = bp1[j];
    #pragma unroll
    for (int k = 0; k < NFEAT; ++k) hp += ewp[w * NFEAT + k] * Wp1[k * UN + j];
    local += fmaxf(hp, 0.f) * Wp2[j];
  }
  red[tid] = local;
  __syncthreads();
  for (int st = 128; st > 0; st >>= 1) { if (tid < st) red[tid] += red[tid + st]; __syncthreads(); }
  if (tid == 0) prior[w] = red[0] + bp2[0];
}

// ---------------- P = hidden @ [W1a | W1b | W1d]  (2048 x 3072, K=768) ----------------
// 128x128 tile, BK=16, 16x16 threads, 8x8 micro-tile (1 B LDS traffic / FMA)
__global__ __launch_bounds__(256) void k_matmul_P(const float* __restrict__ hidden,
                                                  const float* __restrict__ W1,
                                                  float* __restrict__ P) {
  __shared__ float As[16][132];   // [k][m], stride 132 breaks transpose-store conflicts
  __shared__ float Bs[16][128];   // [k][n]
  int bn = blockIdx.x, bm = blockIdx.y;
  int n0 = bn * 128;              // 128 | 1024 -> tiles never straddle segments
  int seg = n0 >> 10;
  int rowbase = (seg == 0) ? 0 : (seg == 1 ? HID : (2 * HID + NFEAT));
  int j0 = n0 & 1023;
  int tid = threadIdx.x;
  int tx = tid & 15, ty = tid >> 4;
  float acc[8][8] = {};
  for (int k0 = 0; k0 < HID; k0 += 16) {
    #pragma unroll
    for (int q = 0; q < 2; ++q) {
      int idx = q * 256 + tid;
      int m = idx >> 2, kg = idx & 3;          // 4 lanes cover 64 contiguous B of a row
      float4 a = *(const float4*)&hidden[(size_t)(bm * 128 + m) * HID + k0 + kg * 4];
      As[kg * 4 + 0][m] = a.x; As[kg * 4 + 1][m] = a.y;
      As[kg * 4 + 2][m] = a.z; As[kg * 4 + 3][m] = a.w;
      int k = idx >> 5, ng = idx & 31;
      float4 b = *(const float4*)&W1[(size_t)(rowbase + k0 + k) * UN + j0 + ng * 4];
      *(float4*)&Bs[k][ng * 4] = b;
    }
    __syncthreads();
    #pragma unroll
    for (int k = 0; k < 16; ++k) {
      float4 a0 = *(const float4*)&As[k][ty * 8];
      float4 a1 = *(const float4*)&As[k][ty * 8 + 4];
      float4 b0 = *(const float4*)&Bs[k][tx * 8];
      float4 b1 = *(const float4*)&Bs[k][tx * 8 + 4];
      float av[8] = {a0.x, a0.y, a0.z, a0.w, a1.x, a1.y, a1.z, a1.w};
      float bv[8] = {b0.x, b0.y, b0.z, b0.w, b1.x, b1.y, b1.z, b1.w};
      #pragma unroll
      for (int i = 0; i < 8; ++i)
        #pragma unroll
        for (int jj = 0; jj < 8; ++jj) acc[i][jj] += av[i] * bv[jj];
    }
    __syncthreads();
  }
  #pragma unroll
  for (int i = 0; i < 8; ++i) {
    float* prow = &P[(size_t)(bm * 128 + ty * 8 + i) * 3072 + n0 + tx * 8];
    *(float4*)prow = make_float4(acc[i][0], acc[i][1], acc[i][2], acc[i][3]);
    *(float4*)(prow + 4) = make_float4(acc[i][4], acc[i][5], acc[i][6], acc[i][7]);
  }
}

// ---------------- fused span_emb write + score + sort key (s-sorted order) ----------------
__global__ __launch_bounds__(256) void k_span(
    const int* __restrict__ ord,
    const float* __restrict__ hidden, const int* __restrict__ starts, const int* __restrict__ ends,
    const float* __restrict__ tok_att, const float* __restrict__ emb_width,
    const float* __restrict__ P, const float* __restrict__ Pc,
    const float* __restrict__ b1, const float* __restrict__ W2,
    const float* __restrict__ b2ptr, const float* __restrict__ prior,
    float* __restrict__ out, float* __restrict__ scores, unsigned long long* __restrict__ keys) {
  int i = ord[blockIdx.x];          // process in ascending-start order for L2 locality
  int s = starts[i], e = ends[i];
  int w = e - s;
  int L = w + 1;
  int tid = threadIdx.x;
  __shared__ float alpha[WMAX];
  __shared__ float red[256];
  if (tid < 64) {
    float v = (tid < L) ? tok_att[s + tid] : -3.0e38f;
    float m = v;
    #pragma unroll
    for (int off = 32; off; off >>= 1) m = fmaxf(m, __shfl_xor(m, off));
    float ex = (tid < L) ? expf(v - m) : 0.0f;
    float sum = ex;
    #pragma unroll
    for (int off = 32; off; off >>= 1) sum += __shfl_xor(sum, off);
    if (tid < L) alpha[tid] = ex / sum;
  }
  __syncthreads();
  const float* hs = hidden + (size_t)s * HID;
  const float* he = hidden + (size_t)e * HID;
  float* orow = out + (size_t)i * SDIM;
  for (int q = tid; q < SDIM / 4; q += 256) {
    int c = q * 4;
    float4 v;
    if (c < HID) v = *(const float4*)(hs + c);
    else if (c < 2 * HID) v = *(const float4*)(he + (c - HID));
    else if (c < 2 * HID + NFEAT) v = *(const float4*)(emb_width + w * NFEAT + (c - 2 * HID));
    else {
      int cc = c - (2 * HID + NFEAT);
      float ax = 0, ay = 0, az = 0, aw = 0;
      for (int t = 0; t < L; ++t) {
        float a = alpha[t];
        float4 hv = *(const float4*)(hidden + (size_t)(s + t) * HID + cc);
        ax += a * hv.x; ay += a * hv.y; az += a * hv.z; aw += a * hv.w;
      }
      v = make_float4(ax, ay, az, aw);
    }
    *(float4*)(orow + c) = v;
  }
  // score: pre_h = b1 + Pa[s] + Pb[e] + Pc[w] + sum_t alpha_t * Pd[s+t]
  int j = tid * 4;
  float4 pre = *(const float4*)(b1 + j);
  float4 pa = *(const float4*)(P + (size_t)s * 3072 + j);
  float4 pb = *(const float4*)(P + (size_t)e * 3072 + 1024 + j);
  float4 pc = *(const float4*)(Pc + w * UN + j);
  pre.x += pa.x + pb.x + pc.x;
  pre.y += pa.y + pb.y + pc.y;
  pre.z += pa.z + pb.z + pc.z;
  pre.w += pa.w + pb.w + pc.w;
  for (int t = 0; t < L; ++t) {
    float a = alpha[t];
    float4 pd = *(const float4*)(P + (size_t)(s + t) * 3072 + 2048 + j);
    pre.x += a * pd.x; pre.y += a * pd.y; pre.z += a * pd.z; pre.w += a * pd.w;
  }
  float4 w2 = *(const float4*)(W2 + j);
  float local = fmaxf(pre.x, 0.f) * w2.x + fmaxf(pre.y, 0.f) * w2.y +
                fmaxf(pre.z, 0.f) * w2.z + fmaxf(pre.w, 0.f) * w2.w;
  red[tid] = local;
  __syncthreads();
  for (int st = 128; st > 0; st >>= 1) { if (tid < st) red[tid] += red[tid + st]; __syncthreads(); }
  if (tid == 0) {
    float sc = red[0] + b2ptr[0] + prior[w];
    scores[i] = sc;
    unsigned u = __float_as_uint(sc);
    u = (u >> 31) ? ~u : (u | 0x80000000u);        // ascending-order map
    unsigned inv = ~u;                             // descending score
    keys[i] = (((unsigned long long)inv) << 32) | (unsigned)i;  // tie: smaller idx first
  }
}

// ---------------- exact argsort via O(n^2) ranking on u64 keys ----------------
__global__ __launch_bounds__(256) void k_rank(const unsigned long long* __restrict__ keys,
                                              int* __restrict__ rank) {
  int ic = blockIdx.x >> 5;     // 20 i-chunks of 2048
  int jc = blockIdx.x & 31;     // 32 j-chunks of 1280
  int tid = threadIdx.x;
  int ibase = ic * 2048 + tid;
  unsigned long long mk[8];
  int cnt[8];
  #pragma unroll
  for (int k = 0; k < 8; ++k) { mk[k] = keys[ibase + k * 256]; cnt[k] = 0; }
  int j0 = jc * 1280;
  #pragma unroll 4
  for (int j = j0; j < j0 + 1280; ++j) {
    unsigned long long kj = keys[j];
    #pragma unroll
    for (int k = 0; k < 8; ++k) cnt[k] += (kj < mk[k]) ? 1 : 0;
  }
  #pragma unroll
  for (int k = 0; k < 8; ++k) if (cnt[k]) atomicAdd(&rank[ibase + k * 256], cnt[k]);
}

__global__ void k_scatter(const int* __restrict__ rank, int* __restrict__ order) {
  int i = blockIdx.x * 256 + threadIdx.x;
  order[rank[i]] = i;
}

// ---------------- greedy NMS: batch-parallel pre-check + register fix-up ----------------
// cross(c; accepted) == exists accepted (s',e') partially overlapping c:
//   (s < s' <= e < e')  or  (s' < s <= e' < e)
__global__ void k_scan(const int* __restrict__ order,
                       const int* __restrict__ starts,
                       const int* __restrict__ ends,
                       int* __restrict__ acc_idx, int* __restrict__ acc_s,
                       int* __restrict__ acc_e, int* __restrict__ acc_count) {
  __shared__ int LE[NT];   // latest_end[tok]
  __shared__ int ES[NT];   // earliest_start[tok]
  int lane = threadIdx.x;
  for (int t = lane; t < NT; t += 64) { LE[t] = -1; ES[t] = NT; }
  __syncthreads();
  int count = 0;
  for (int base = 0; base < NC && count < NTOP; base += 64) {
    int ci = order[base + lane];
    int sv = starts[ci];
    int ev = ends[ci];
    // parallel pre-check vs all spans accepted before this batch
    bool pc = false;
    for (int t = sv; t <= ev; ++t) {
      int l = LE[t], es2 = ES[t];
      pc = pc || ((t > sv) && (l > ev)) || ((t < ev) && (es2 < sv));
    }
    unsigned long long pm = __ballot(pc);
    // serial resolution vs batch-local accepts held in lane registers
    int localCount = 0;
    int ls = 0, le = -1, li = 0;
    for (int t = 0; t < 64; ++t) {
      int s = __shfl(sv, t);
      int e = __shfl(ev, t);
      int cidx = __shfl(ci, t);
      bool ov = (lane < localCount) &&
                (((s < ls) && (ls <= e) && (e < le)) ||
                 ((ls < s) && (s <= le) && (le < e)));
      bool cross = (((pm >> t) & 1ull) != 0) || __any(ov);
      if (!cross) {
        if (lane == localCount) { ls = s; le = e; li = cidx; }
        localCount++;
        count++;
        if (count >= NTOP) break;
      }
    }
    // flush batch-local accepts to global list + LDS state
    int cbase = count - localCount;
    if (lane < localCount) {
      acc_idx[cbase + lane] = li;
      acc_s[cbase + lane] = ls;
      acc_e[cbase + lane] = le;
      atomicMax(&LE[ls], le);
      atomicMin(&ES[le], ls);
    }
    __syncthreads();
  }
  if (lane == 0) acc_count[0] = count;
}

// ---------------- sort accepted by (start,end), write scalar outputs ----------------
__global__ __launch_bounds__(512) void k_outputs(const int* __restrict__ acc_idx,
                                                 const int* __restrict__ acc_s,
                                                 const int* __restrict__ acc_e,
                                                 const int* __restrict__ acc_count,
                                                 const float* __restrict__ scores,
                                                 const int* __restrict__ speaker,
                                                 float* __restrict__ out,
                                                 int* __restrict__ sortedIdx) {
  __shared__ int ks[NTOP];
  int tid = threadIdx.x;
  int count = acc_count[0];
  int key = 0x7FFFFFFF;
  if (tid < count) key = acc_s[tid] * (NT + 1) + acc_e[tid];
  ks[tid] = key;
  __syncthreads();
  if (tid < count) {
    int r = 0;
    for (int b = 0; b < count; ++b) {
      int kb = ks[b];
      r += ((kb < key) || (kb == key && b < tid)) ? 1 : 0;
    }
    int ci = acc_idx[tid];
    out[OFF_IDX + r] = (float)ci;
    out[OFF_S + r]   = (float)acc_s[tid];
    out[OFF_E + r]   = (float)acc_e[tid];
    out[OFF_SC + r]  = scores[ci];
    out[OFF_SP + r]  = (float)speaker[acc_s[tid]];
    sortedIdx[r] = ci;
  }
  __syncthreads();
  if (tid >= count) {   // ref: where(valid, picked, picked[0])
    out[OFF_IDX + tid] = out[OFF_IDX];
    out[OFF_S + tid]   = out[OFF_S];
    out[OFF_E + tid]   = out[OFF_E];
    out[OFF_SC + tid]  = out[OFF_SC];
    out[OFF_SP + tid]  = out[OFF_SP];
    sortedIdx[tid] = sortedIdx[0];
  }
}

// ---------------- gather pruned_emb rows from span_emb region of d_out ----------------
__global__ __launch_bounds__(256) void k_copy_emb(const int* __restrict__ sortedIdx,
                                                  float* __restrict__ out) {
  int r = blockIdx.x;
  int ci = sortedIdx[r];
  const float* src = out + (size_t)ci * SDIM;
  float* dst = out + OFF_PEMB + (size_t)r * SDIM;
  for (int q = threadIdx.x; q < SDIM / 4; q += 256) {
    ((float4*)dst)[q] = ((const float4*)src)[q];
  }
}

extern "C" void kernel_launch(void* const* d_in, const int* in_sizes, int n_in,
                              void* d_out, int out_size, void* d_ws, size_t ws_size,
                              hipStream_t stream) {
  const float* hidden   = (const float*)d_in[0];
  const int*   starts   = (const int*)d_in[1];
  const int*   ends     = (const int*)d_in[2];
  const int*   speaker  = (const int*)d_in[3];
  const float* w_attn   = (const float*)d_in[4];
  const float* b_attn   = (const float*)d_in[5];
  const float* W1       = (const float*)d_in[6];
  const float* b1       = (const float*)d_in[7];
  const float* W2       = (const float*)d_in[8];
  const float* b2       = (const float*)d_in[9];
  const float* embw     = (const float*)d_in[10];
  const float* ewp      = (const float*)d_in[11];
  const float* Wp1      = (const float*)d_in[12];
  const float* bp1      = (const float*)d_in[13];
  const float* Wp2      = (const float*)d_in[14];
  const float* bp2      = (const float*)d_in[15];
  float* out = (float*)d_out;

  float* f = (float*)d_ws;
  float* P       = f;                    // 2048*3072
  float* tok_att = P + 6291456;          // 2048
  float* Pc      = tok_att + 2048;       // 20*1024
  float* prior   = Pc + 20480;           // 20 (pad 32)
  float* scores  = prior + 32;           // 40960
  unsigned long long* keys = (unsigned long long*)(scores + 40960);  // 40960 u64
  int* rank      = (int*)(keys + 40960);
  int* order     = rank + 40960;
  int* acc_idx   = order + 40960;
  int* acc_s     = acc_idx + NTOP;
  int* acc_e     = acc_s + NTOP;
  int* acc_count = acc_e + NTOP;
  int* sortedIdx = acc_count + 4;
  int* hist      = sortedIdx + NTOP;
  int* cursor    = hist + NT;
  int* ord       = cursor + NT;          // 40960

  // counting sort of candidates by start token (for k_span L2 locality)
  k_zero<<<dim3(8), dim3(256), 0, stream>>>(hist, NT);
  k_zero<<<dim3(160), dim3(256), 0, stream>>>(rank, NC);
  k_hist<<<dim3(160), dim3(256), 0, stream>>>(starts, hist);
  k_prefix<<<dim3(1), dim3(256), 0, stream>>>(hist, cursor);
  k_place<<<dim3(160), dim3(256), 0, stream>>>(starts, cursor, ord);

  k_tok_att<<<dim3(512), dim3(256), 0, stream>>>(hidden, w_attn, b_attn, tok_att);
  k_pc<<<dim3(80), dim3(256), 0, stream>>>(embw, W1, Pc);
  k_prior<<<dim3(20), dim3(256), 0, stream>>>(ewp, Wp1, bp1, Wp2, bp2, prior);
  k_matmul_P<<<dim3(24, 16), dim3(256), 0, stream>>>(hidden, W1, P);
  k_span<<<dim3(NC), dim3(256), 0, stream>>>(ord, hidden, starts, ends, tok_att, embw, P, Pc,
                                             b1, W2, b2, prior, out, scores, keys);
  k_rank<<<dim3(640), dim3(256), 0, stream>>>(keys, rank);
  k_scatter<<<dim3(160), dim3(256), 0, stream>>>(rank, order);
  k_scan<<<dim3(1), dim3(64), 0, stream>>>(order, starts, ends, acc_idx, acc_s, acc_e, acc_count);
  k_outputs<<<dim3(1), dim3(512), 0, stream>>>(acc_idx, acc_s, acc_e, acc_count, scores,
                                               speaker, out, sortedIdx);
  k_copy_emb<<<dim3(NTOP), dim3(256), 0, stream>>>(sortedIdx, out);
}